// Round 1
// 501.162 us; speedup vs baseline: 1.1236x; 1.1236x over previous
//
#include <hip/hip_runtime.h>

typedef unsigned short u16;
typedef unsigned int u32;
typedef float f32x4 __attribute__((ext_vector_type(4)));
typedef float f32x2 __attribute__((ext_vector_type(2)));
typedef short s16x8 __attribute__((ext_vector_type(8)));
typedef __bf16 bf16x8 __attribute__((ext_vector_type(8)));

#define NNODE 50000
#define NEDGE 200000
#define INV_SQRT3 0.57735026918962576f
#define INV_SQRT_FAN 0.0034938562148434216f  /* 1/sqrt(256^2+128^2) */

__device__ inline float b2f(u16 x) {
    unsigned u = ((unsigned)x) << 16;
    return __builtin_bit_cast(float, u);
}
__device__ inline u16 f2b(float f) {
    unsigned u = __builtin_bit_cast(unsigned, f);
    unsigned r = u + 0x7FFFu + ((u >> 16) & 1u);
    return (u16)(r >> 16);
}
__device__ inline float silu(float v) { return v / (1.f + __expf(-v)); }

__device__ inline float ld1(const void* p, long i, int m) {
    return m ? ((const float*)p)[i] : b2f(((const u16*)p)[i]);
}
__device__ inline void stout(void* o, long i, float v, int m) {
    if (m) ((float*)o)[i] = v; else ((u16*)o)[i] = f2b(v);
}

// ---------------- fp8 e4m3fn codec ----------------
#if defined(__has_builtin)
# if __has_builtin(__builtin_amdgcn_cvt_pk_f32_fp8) && __has_builtin(__builtin_amdgcn_cvt_pk_fp8_f32)
#  define HAVE_FP8 1
# endif
#endif
#ifndef HAVE_FP8
# define HAVE_FP8 0
#endif

__device__ inline int f2e4m3_soft(float f) {
    unsigned u = __builtin_bit_cast(unsigned, f);
    int s = (u >> 24) & 0x80;
    float a = __builtin_fabsf(f);
    if (a >= 464.f) return s | 0x7E;
    if (a < 0.015625f) {
        int q = (int)(a * 512.f + 0.5f);
        return s | q;
    }
    int e = (int)((u >> 23) & 0xFF) - 127;
    unsigned m = u & 0x7FFFFF;
    unsigned mq = (m + 0x80000) >> 20;
    if (mq == 8) { mq = 0; e += 1; }
    if (e > 8) return s | 0x7E;
    return s | ((e + 7) << 3) | (int)mq;
}
__device__ inline float e4m3f_soft(int b) {
    int em = b & 0x7F;
    float v;
    if (em >> 3) {
        unsigned bits = ((unsigned)((em >> 3) + 120) << 23) | ((unsigned)(em & 7) << 20);
        v = __builtin_bit_cast(float, bits);
    } else {
        v = (float)em * 0.001953125f;
    }
    return (b & 0x80) ? -v : v;
}
__device__ inline int enc2(float a, float b) {
#if HAVE_FP8
    return __builtin_amdgcn_cvt_pk_fp8_f32(a, b, 0, false) & 0xFFFF;
#else
    return f2e4m3_soft(a) | (f2e4m3_soft(b) << 8);
#endif
}
__device__ inline unsigned char enc1(float a) { return (unsigned char)(enc2(a, a) & 0xFF); }

__device__ inline float dot8(unsigned p, unsigned x, float acc) {
#if HAVE_FP8
    f32x2 p0 = __builtin_amdgcn_cvt_pk_f32_fp8((int)p, false);
    f32x2 p1 = __builtin_amdgcn_cvt_pk_f32_fp8((int)p, true);
    f32x2 x0 = __builtin_amdgcn_cvt_pk_f32_fp8((int)x, false);
    f32x2 x1 = __builtin_amdgcn_cvt_pk_f32_fp8((int)x, true);
    return acc + p0.x * x0.x + p0.y * x0.y + p1.x * x1.x + p1.y * x1.y;
#else
    float r = acc;
#pragma unroll
    for (int i = 0; i < 4; ++i)
        r += e4m3f_soft((p >> (8 * i)) & 0xFF) * e4m3f_soft((x >> (8 * i)) & 0xFF);
    return r;
#endif
}
__device__ inline float dot2(unsigned p, unsigned x, float acc) {
#if HAVE_FP8
    f32x2 p0 = __builtin_amdgcn_cvt_pk_f32_fp8((int)p, false);
    f32x2 x0 = __builtin_amdgcn_cvt_pk_f32_fp8((int)x, false);
    return acc + p0.x * x0.x + p0.y * x0.y;
#else
    return acc + e4m3f_soft(p & 0xFF) * e4m3f_soft(x & 0xFF)
               + e4m3f_soft((p >> 8) & 0xFF) * e4m3f_soft((x >> 8) & 0xFF);
#endif
}

// MFMA wrapper tolerant to either builtin signature.
template <typename V>
__device__ auto mfma_sel(V a, V b, f32x4 c, int)
    -> decltype(__builtin_amdgcn_mfma_f32_16x16x32_bf16(a, b, c, 0, 0, 0)) {
    return __builtin_amdgcn_mfma_f32_16x16x32_bf16(a, b, c, 0, 0, 0);
}
template <typename V>
__device__ f32x4 mfma_sel(V a, V b, f32x4 c, long) {
    bf16x8 aa = __builtin_bit_cast(bf16x8, a);
    bf16x8 bb = __builtin_bit_cast(bf16x8, b);
    return __builtin_amdgcn_mfma_f32_16x16x32_bf16(aa, bb, c, 0, 0, 0);
}
__device__ inline f32x4 mfma_bf16(s16x8 a, s16x8 b, f32x4 c) {
    return mfma_sel(a, b, c, 0);
}

// ---------------- async global -> LDS (16 B per lane, wave-uniform LDS base) ----
typedef __attribute__((address_space(1))) u32 AS1u32;
typedef __attribute__((address_space(3))) u32 AS3u32;
__device__ __forceinline__ void async16(const void* g, void* l) {
    __builtin_amdgcn_global_load_lds((AS1u32*)g, (AS3u32*)l, 16, 0, 0);
}

// ---------------- detect input storage dtype ----------------
__global__ __launch_bounds__(256) void detect_k(const void* __restrict__ h, int* __restrict__ flag) {
    int t = threadIdx.x;
    u16 w = ((const u16*)h)[2 * t];
    int tb = (w >> 8) & 0x7F;
    bool pl = (tb >= 0x38 && tb <= 0x41);
    unsigned long long b = __ballot(pl);
    __shared__ int cnt[4];
    if ((t & 63) == 0) cnt[t >> 6] = __popcll(b);
    __syncthreads();
    if (t == 0) {
        int s = cnt[0] + cnt[1] + cnt[2] + cnt[3];
        flag[0] = (s < 128) ? 1 : 0;  // 1 = f32 storage
    }
}

// ---------------- prep: transposes / packs / w_eff ----------------
__global__ __launch_bounds__(256) void prep_misc_k(
    const void* __restrict__ W00, const void* __restrict__ W11,
    const void* __restrict__ bW1, const void* __restrict__ Wv,
    const void* __restrict__ Wcoord, const void* __restrict__ aW2,
    const void* __restrict__ bW2,
    u16* __restrict__ W00T, u16* __restrict__ W1p, u16* __restrict__ W2p,
    float* __restrict__ w1tp, float* __restrict__ w_eff,
    u16* __restrict__ W2ah, u16* __restrict__ W11T,
    const int* __restrict__ mflag)
{
    const int m = *mflag;
    int u = blockIdx.x * 256 + threadIdx.x;
    if (u < 65536) {                 // W00T[j][i] = W00[i][j]
        int j = u >> 8, i = u & 255;
        W00T[u] = f2b(ld1(W00, (long)i * 256 + j, m));
    } else if (u < 81920) {          // W1p: bond W1 fragment pack
        int v = u - 65536;
        int j = v & 7, ln = (v >> 3) & 63, tk = v >> 9;  // tk 0..31
        int tn = tk >> 1, kt = tk & 1;
        int hrow = tn * 16 + (ln & 15);
        int k = kt * 32 + (ln >> 4) * 8 + j;
        W1p[v] = f2b(ld1(bW1, (long)hrow * 65 + 1 + k, m));
    } else if (u < 86016) {          // W2p: bond W2 fragment pack (padded o>=5 -> 0)
        int v = u - 81920;
        int j = v & 7, ln = (v >> 3) & 63, kt = v >> 9;  // kt 0..7
        int o = ln & 15;
        int k = kt * 32 + (ln >> 4) * 8 + j;
        W2p[v] = (o < 5) ? f2b(ld1(bW2, (long)o * 256 + k, m)) : (u16)0;
    } else if (u < 86272) {          // w1tp
        int hd = u - 86016;
        w1tp[hd] = ld1(bW1, (long)hd * 65, m);
    } else if (u < 86400) {          // w_eff
        int c = u - 86272;
        float acc = 0.f;
        for (int d = 0; d < 128; ++d)
            acc += ld1(Wcoord, d, m) * ld1(Wv, (long)d * 128 + c, m);
        w_eff[c] = acc;
    } else if (u < 90496) {          // atom W2 (16x256)
        int v = u - 86400;
        W2ah[v] = f2b(ld1(aW2, v, m));
    } else if (u < 106880) {         // W11T[d][c] = W11[c][d]
        int v = u - 90496;
        int d = v >> 7, c = v & 127;
        W11T[v] = f2b(ld1(W11, (long)c * 128 + d, m));
    }
}

// W1s = atom_W1 @ Ws_w; b1p = atom_W1@Ws_b + atom_b1
__global__ __launch_bounds__(256) void prep_w1s_k(
    const void* __restrict__ aW1, const void* __restrict__ Wsw,
    const void* __restrict__ Wsb, const void* __restrict__ ab1,
    u16* __restrict__ W1sh, float* __restrict__ b1p,
    const int* __restrict__ mflag)
{
    const int m = *mflag;
    int hd = blockIdx.x, s = threadIdx.x;
    float acc = 0.f;
    for (int j = 0; j < 256; ++j)
        acc += ld1(aW1, (long)hd * 256 + j, m) * ld1(Wsw, (long)j * 256 + s, m);
    W1sh[hd * 256 + s] = f2b(acc);
    if (s == 0) {
        float b = ld1(ab1, hd, m);
        for (int j = 0; j < 256; ++j)
            b += ld1(aW1, (long)hd * 256 + j, m) * ld1(Wsb, j, m);
        b1p[hd] = b;
    }
}

// ---------------- shared pipelined 128x128 GEMM core ----------------
// C[128 x 128] += A[128 x K] * B^T, B stored row-major [outcol][K] (k-contiguous).
// LDS: S[16384] u16 = A dbuf (2 x 4 KB) | B dbuf (2 x 4 KB).
// Schedule (T3-min): stage(t+1) issued BEFORE compute(t); one __syncthreads per
// K-step drains vmcnt+lgkm (compiler-inserted) -> loads fly during MFMA phase.
__device__ __forceinline__ void gemm_core_128(
    const void* __restrict__ Aptr, int lda, int a_f32,
    const u16* __restrict__ Bt, int ldb, int bcol0,
    long bm0, int K, u16* __restrict__ S, f32x4 acc[4][4])
{
    u16* As = S;            // [2][4096] u16, tile layout linear [row][32]
    u16* Bs = S + 8192;     // [2][4096] u16
    int tid = threadIdx.x;
    int lane = tid & 63, wave = tid >> 6;
    int sr = lane >> 2, sc = (lane & 3) * 8;   // lane -> (row-in-16, k-offset)

    auto stage = [&](int buf, int k0) {
        // B: always u16 weights in workspace, fully in-bounds.
#pragma unroll
        for (int i = 0; i < 2; ++i) {
            int row = wave * 32 + i * 16 + sr;
            async16(Bt + (long)(bcol0 + row) * ldb + k0 + sc,
                    Bs + buf * 4096 + wave * 1024 + i * 512);
        }
        if (!a_f32) {
            // bf16/u16 A: direct global->LDS. OOB rows clamp to last node (the
            // garbage C rows are never written).
#pragma unroll
            for (int i = 0; i < 2; ++i) {
                int row = wave * 32 + i * 16 + sr;
                long grow = bm0 + row; if (grow >= NNODE) grow = NNODE - 1;
                async16((const u16*)Aptr + grow * (long)lda + k0 + sc,
                        As + buf * 4096 + wave * 1024 + i * 512);
            }
        } else {
            // f32 A fallback: reg-stage + convert into the same linear layout.
            int r = tid >> 2, c = (tid & 3) * 8;
#pragma unroll
            for (int p = 0; p < 2; ++p) {
                int row = p * 64 + r;
                long grow = bm0 + row; if (grow >= NNODE) grow = NNODE - 1;
                const float* ap = (const float*)Aptr + grow * (long)lda + k0 + c;
                float4 a0 = *(const float4*)ap;
                float4 a1 = *(const float4*)(ap + 4);
                u16 t[8] = {f2b(a0.x), f2b(a0.y), f2b(a0.z), f2b(a0.w),
                            f2b(a1.x), f2b(a1.y), f2b(a1.z), f2b(a1.w)};
                *(ushort4*)(As + buf * 4096 + row * 32 + c)     = *(const ushort4*)&t[0];
                *(ushort4*)(As + buf * 4096 + row * 32 + c + 4) = *(const ushort4*)&t[4];
            }
        }
    };

    int NT = K >> 5;
    stage(0, 0);
    __syncthreads();
    int wm = (wave & 1) * 64, wn = (wave >> 1) * 64;
    int lm = lane & 15, quad = lane >> 4;
    for (int t = 0; t < NT; ++t) {
        int cur = t & 1;
        if (t + 1 < NT) stage(cur ^ 1, (t + 1) * 32);
        const u16* Ac = As + cur * 4096;
        const u16* Bc = Bs + cur * 4096;
        s16x8 af[4], bfr[4];
#pragma unroll
        for (int q = 0; q < 4; ++q) {
            af[q]  = *(const s16x8*)(Ac + (wm + q * 16 + lm) * 32 + quad * 8);
            bfr[q] = *(const s16x8*)(Bc + (wn + q * 16 + lm) * 32 + quad * 8);
        }
#pragma unroll
        for (int i = 0; i < 4; ++i)
#pragma unroll
            for (int j = 0; j < 4; ++j)
                acc[i][j] = mfma_bf16(af[i], bfr[j], acc[i][j]);
        __syncthreads();
    }
}

// ---------------- atom MLP layer1 (pipelined core + LDS-staged coalesced store) --
__global__ __launch_bounds__(256) void mlp1_k(
    const void* __restrict__ A, const u16* __restrict__ Bh,
    const float* __restrict__ b1p, u16* __restrict__ hid,
    const int* __restrict__ mflag)
{
    __shared__ __align__(16) u16 S[16384];
    int bid = blockIdx.x;
    int x = bid & 7, s = bid >> 3;
    int rb = (s >> 1) * 8 + x, cb = s & 1;
    if (rb >= 391) return;
    const int m = *mflag;
    long bm0 = (long)rb * 128;
    int bn0 = cb * 128;
    f32x4 acc[4][4] = {};
    gemm_core_128(A, 640, m, Bh, 256, bn0, bm0, 256, S, acc);

    int tid = threadIdx.x, lane = tid & 63, wave = tid >> 6;
    int wm = (wave & 1) * 64, wn = (wave >> 1) * 64;
    int lm = lane & 15, quad = lane >> 4;
    // epilogue: silu+bias -> bf16 C-tile in LDS (staging bufs are free now)
#pragma unroll
    for (int j = 0; j < 4; ++j) {
        int col = wn + j * 16 + lm;
        float bb = b1p[bn0 + col];
#pragma unroll
        for (int i = 0; i < 4; ++i)
#pragma unroll
            for (int rr = 0; rr < 4; ++rr) {
                int row = wm + i * 16 + quad * 4 + rr;
                S[row * 128 + col] = f2b(silu(acc[i][j][rr] + bb));
            }
    }
    __syncthreads();
    // coalesced 16 B/lane store
#pragma unroll
    for (int v = 0; v < 8; ++v) {
        int idx = v * 256 + tid;
        int row = idx >> 4, seg = idx & 15;
        long grow = bm0 + row;
        if (grow < NNODE)
            *(uint4*)(hid + grow * 256 + bn0 + seg * 8) =
                *(const uint4*)(S + row * 128 + seg * 8);
    }
}

// ---------------- atom MLP layer2 ----------------
__global__ __launch_bounds__(256) void mlp_l2_k(
    const u16* __restrict__ hid, const u16* __restrict__ W2h,
    const void* __restrict__ b2v, void* __restrict__ out,
    const int* __restrict__ mflag)
{
    const int m = *mflag;
    int tid = threadIdx.x, lane = tid & 63, w = tid >> 6;
    int lm = lane & 15, quad = lane >> 4;
    int m0 = blockIdx.x * 64 + w * 16;
    int arow = m0 + lm; if (arow >= NNODE) arow = NNODE - 1;
    const u16* ap = hid + (long)arow * 256;
    const u16* wp = W2h + (long)lm * 256;
    f32x4 acc = {0.f, 0.f, 0.f, 0.f};
#pragma unroll
    for (int k0 = 0; k0 < 256; k0 += 32) {
        s16x8 a  = *(const s16x8*)(ap + k0 + quad * 8);
        s16x8 bh = *(const s16x8*)(wp + k0 + quad * 8);
        acc = mfma_bf16(a, bh, acc);
    }
    float b2 = ld1(b2v, lm, m);
#pragma unroll
    for (int rr = 0; rr < 4; ++rr) {
        int grow = m0 + quad * 4 + rr;
        if (grow < NNODE)
            stout(out, (long)grow * 16 + lm, acc[rr] + b2, m);
    }
}

// ---------------- merged pack: X8 (planar vec), xvp, r0 — one pass over h -------
__global__ __launch_bounds__(256) void packx8_k(
    const void* __restrict__ h, u16* __restrict__ xvp,
    const float* __restrict__ w_eff, unsigned char* __restrict__ X8,
    void* __restrict__ out, const int* __restrict__ mflag)
{
    const int m = *mflag;
    int lane = threadIdx.x & 63, w = threadIdx.x >> 6;
    int node = blockIdx.x * 4 + w;
    if (node >= NNODE) return;
    // scalar part: 4 elems/lane -> fp8
    float s4[4];
    if (m) {
        float4 v = *(const float4*)((const float*)h + (long)node * 640 + lane * 4);
        s4[0] = v.x; s4[1] = v.y; s4[2] = v.z; s4[3] = v.w;
    } else {
        ushort4 v = *(const ushort4*)((const u16*)h + (long)node * 640 + lane * 4);
        s4[0] = b2f(v.x); s4[1] = b2f(v.y); s4[2] = b2f(v.z); s4[3] = b2f(v.w);
    }
    unsigned sp = (unsigned)enc2(s4[0], s4[1]) | ((unsigned)enc2(s4[2], s4[3]) << 16);
    *(unsigned*)(X8 + (long)node * 640 + lane * 4) = sp;
    // vector part: 6 elems/lane (c=2*lane, 2*lane+1; z=0,1,2 interleaved)
    float a[6];
    if (m) {
        const float* p = (const float*)h + (long)node * 640 + 256 + lane * 6;
        float2 v0 = *(const float2*)p;
        float2 v1 = *(const float2*)(p + 2);
        float2 v2 = *(const float2*)(p + 4);
        a[0] = v0.x; a[1] = v0.y; a[2] = v1.x; a[3] = v1.y; a[4] = v2.x; a[5] = v2.y;
    } else {
        const u16* p = (const u16*)h + (long)node * 640 + 256 + lane * 6;
        ushort2 v0 = *(const ushort2*)p;
        ushort2 v1 = *(const ushort2*)(p + 2);
        ushort2 v2 = *(const ushort2*)(p + 4);
        a[0] = b2f(v0.x); a[1] = b2f(v0.y); a[2] = b2f(v1.x);
        a[3] = b2f(v1.y); a[4] = b2f(v2.x); a[5] = b2f(v2.y);
    }
#pragma unroll
    for (int z = 0; z < 3; ++z) {
        unsigned pk = (unsigned)f2b(a[z]) | ((unsigned)f2b(a[z + 3]) << 16);
        *(unsigned*)(xvp + (long)z * 6400000 + (long)node * 128 + lane * 2) = pk;
        // planar fp8: X8[node][256 + z*128 + c], c = 2*lane, 2*lane+1
        *(unsigned short*)(X8 + (long)node * 640 + 256 + z * 128 + lane * 2) =
            (unsigned short)enc2(a[z], a[z + 3]);
    }
    // fused r0
    float2 we = *(const float2*)(w_eff + lane * 2);
    float s0 = a[0] * we.x + a[3] * we.y;
    float s1 = a[1] * we.x + a[4] * we.y;
    float s2 = a[2] * we.x + a[5] * we.y;
#pragma unroll
    for (int off = 32; off > 0; off >>= 1) {
        s0 += __shfl_down(s0, off);
        s1 += __shfl_down(s1, off);
        s2 += __shfl_down(s2, off);
    }
    if (lane == 0) {
        stout(out, 800000L + (long)node * 3 + 0, s0, m);
        stout(out, 800000L + (long)node * 3 + 1, s1, m);
        stout(out, 800000L + (long)node * 3 + 2, s2, m);
    }
}

// ---------------- combined PQ GEMM -> fp8 (planar Q), pipelined core ------------
// cb 0,1: P = Xs@W00 (K=256) -> cols cb*128. cb 2,3,4: Q_z = xvp_z@W11 (K=128)
// -> PLANAR cols 256 + z*128 (matches packx8_k's X8 layout).
__global__ __launch_bounds__(256) void gemm8n_k(
    const void* __restrict__ h, const u16* __restrict__ xvp,
    const u16* __restrict__ W00T, const u16* __restrict__ W11T,
    unsigned char* __restrict__ PQ8,
    float s00, float s11, const int* __restrict__ mflag)
{
    __shared__ __align__(16) u16 S[16384];
    int bid = blockIdx.x;
    int x = bid & 7, s = bid >> 3;
    int rb = (s / 5) * 8 + x, cb = s % 5;
    if (rb >= 391) return;
    const int m = *mflag;
    const bool qp = (cb >= 2);
    int z = cb - 2;
    long bm0 = (long)rb * 128;
    f32x4 acc[4][4] = {};
    if (qp)
        gemm_core_128(xvp + (long)z * 6400000, 128, 0, W11T, 128, 0, bm0, 128, S, acc);
    else
        gemm_core_128(h, 640, m, W00T, 256, cb * 128, bm0, 256, S, acc);

    float scale = qp ? s11 : s00;
    int colbase = qp ? (256 + z * 128) : cb * 128;
    unsigned char* C8 = (unsigned char*)S;
    int tid = threadIdx.x, lane = tid & 63, wave = tid >> 6;
    int wm = (wave & 1) * 64, wn = (wave >> 1) * 64;
    int lm = lane & 15, quad = lane >> 4;
#pragma unroll
    for (int j = 0; j < 4; ++j) {
        int col = wn + j * 16 + lm;
#pragma unroll
        for (int i = 0; i < 4; ++i)
#pragma unroll
            for (int rr = 0; rr < 4; ++rr) {
                int row = wm + i * 16 + quad * 4 + rr;
                C8[row * 128 + col] = enc1(scale * acc[i][j][rr]);
            }
    }
    __syncthreads();
#pragma unroll
    for (int v = 0; v < 4; ++v) {
        int idx = v * 256 + tid;
        int row = idx >> 3, seg = idx & 7;
        long grow = bm0 + row;
        if (grow < NNODE)
            *(uint4*)(PQ8 + grow * 640 + colbase + seg * 16) =
                *(const uint4*)(C8 + row * 128 + seg * 16);
    }
}

// ---------------- bond head: MFMA both layers, per-wave LDS transpose -----------
__global__ __launch_bounds__(256) void bond_fused_k(
    const void* __restrict__ A, const u16* __restrict__ W1p,
    const void* __restrict__ b1v, const u16* __restrict__ W2p,
    const void* __restrict__ b2v, const float* __restrict__ tp,
    const float* __restrict__ w1tp, void* __restrict__ out, long obase,
    const int* __restrict__ mflag)
{
    const int m = *mflag;
    __shared__ __align__(16) u16 hidS[4][16][264];
    int tid = threadIdx.x, lane = tid & 63, w = tid >> 6;
    int lm = lane & 15, quad = lane >> 4;
    int e0 = (blockIdx.x * 4 + w) * 16;
    s16x8 af0, af1;
    long base = (long)(e0 + lm) * 64 + quad * 8;
    if (m) {
        const float* ap = (const float*)A + base;
        float4 a0 = *(const float4*)ap,        a1 = *(const float4*)(ap + 4);
        float4 a2 = *(const float4*)(ap + 32), a3 = *(const float4*)(ap + 36);
        u16 t0[8] = {f2b(a0.x), f2b(a0.y), f2b(a0.z), f2b(a0.w),
                     f2b(a1.x), f2b(a1.y), f2b(a1.z), f2b(a1.w)};
        u16 t1[8] = {f2b(a2.x), f2b(a2.y), f2b(a2.z), f2b(a2.w),
                     f2b(a3.x), f2b(a3.y), f2b(a3.z), f2b(a3.w)};
        af0 = *(const s16x8*)t0; af1 = *(const s16x8*)t1;
    } else {
        af0 = *(const s16x8*)((const u16*)A + base);
        af1 = *(const s16x8*)((const u16*)A + base + 32);
    }
    float4 tpv = *(const float4*)(tp + e0 + quad * 4);
    float tpr[4] = {tpv.x, tpv.y, tpv.z, tpv.w};
    f32x4 acc1[16];
#pragma unroll
    for (int tn = 0; tn < 16; ++tn) {
        s16x8 b0 = *(const s16x8*)(W1p + ((tn * 2 + 0) * 64 + lane) * 8);
        s16x8 b1f = *(const s16x8*)(W1p + ((tn * 2 + 1) * 64 + lane) * 8);
        f32x4 a = {0.f, 0.f, 0.f, 0.f};
        a = mfma_bf16(af0, b0, a);
        a = mfma_bf16(af1, b1f, a);
        acc1[tn] = a;
    }
#pragma unroll
    for (int tn = 0; tn < 16; ++tn) {
        int hcol = tn * 16 + lm;
        float bb = ld1(b1v, hcol, m);
        float wt = w1tp[hcol];
#pragma unroll
        for (int rr = 0; rr < 4; ++rr)
            hidS[w][quad * 4 + rr][hcol] = f2b(silu(acc1[tn][rr] + bb + tpr[rr] * wt));
    }
    f32x4 acc2 = {0.f, 0.f, 0.f, 0.f};
#pragma unroll
    for (int kt = 0; kt < 8; ++kt) {
        s16x8 a = *(const s16x8*)&hidS[w][lm][kt * 32 + quad * 8];
        s16x8 b = *(const s16x8*)(W2p + (kt * 64 + lane) * 8);
        acc2 = mfma_bf16(a, b, acc2);
    }
    if (lm < 5) {
        float b2 = ld1(b2v, lm, m);
#pragma unroll
        for (int rr = 0; rr < 4; ++rr) {
            int e = e0 + quad * 4 + rr;
            stout(out, obase + (long)e * 5 + lm, acc2[rr] + b2, m);
        }
    }
}

// ---------------- tp: wave-per-edge fp8 640-dot ----------------
__global__ __launch_bounds__(256) void tp_k(
    const int* __restrict__ ei, const unsigned char* __restrict__ PQ8,
    const unsigned char* __restrict__ X8, float* __restrict__ tp)
{
    int wave = threadIdx.x >> 6, lane = threadIdx.x & 63;
    int e = blockIdx.x * 4 + wave;
    if (e >= NEDGE) return;
    int row = ei[e], col = ei[NEDGE + e];
    const unsigned char* pq = PQ8 + (long)row * 640;
    const unsigned char* xp = X8 + (long)col * 640;
    uint2 pw = *(const uint2*)(pq + lane * 8);
    uint2 xw = *(const uint2*)(xp + lane * 8);
    unsigned pt = *(const unsigned short*)(pq + 512 + lane * 2);
    unsigned xt = *(const unsigned short*)(xp + 512 + lane * 2);
    float acc = 0.f;
    acc = dot8(pw.x, xw.x, acc);
    acc = dot8(pw.y, xw.y, acc);
    acc = dot2(pt, xt, acc);
#pragma unroll
    for (int off = 32; off > 0; off >>= 1) acc += __shfl_down(acc, off);
    if (lane == 0) tp[e] = acc * 0.0625f;
}

extern "C" void kernel_launch(void* const* d_in, const int* in_sizes, int n_in,
                              void* d_out, int out_size, void* d_ws, size_t ws_size,
                              hipStream_t stream) {
    (void)in_sizes; (void)n_in; (void)out_size; (void)ws_size;
    const void* h      = d_in[0];
    const void* e_fin  = d_in[1];
    const int*  ei     = (const int*)d_in[4];
    const void* Ws_w   = d_in[5];
    const void* Ws_b   = d_in[6];
    const void* Wv     = d_in[7];
    const void* Wcoord = d_in[8];
    const void* W00    = d_in[9];
    const void* W11    = d_in[10];
    const void* aW1    = d_in[11];
    const void* ab1    = d_in[12];
    const void* aW2    = d_in[13];
    const void* ab2    = d_in[14];
    const void* bW1    = d_in[15];
    const void* bb1    = d_in[16];
    const void* bW2    = d_in[17];
    const void* bb2    = d_in[18];

    char* ws = (char*)d_ws;
    int*   mflag = (int*)(ws + 0);
    float* w1tp  = (float*)(ws + 512);
    float* w_eff = (float*)(ws + 2048);
    float* b1p   = (float*)(ws + 3072);
    u16*   W00T  = (u16*)(ws + 4096);       // -> 135168
    u16*   W1p   = (u16*)(ws + 135168);     // -> 167936
    u16*   W2p   = (u16*)(ws + 167936);     // -> 176128
    u16*   W1sh  = (u16*)(ws + 176128);     // -> 307200
    u16*   W2ah  = (u16*)(ws + 307200);     // -> 315392
    u16*   W11T  = (u16*)(ws + 315392);     // -> 348160
    float* tp    = (float*)(ws + 348160);   // -> 1148160
    char*  R     = ws + 1149184;
    unsigned char* PQ8  = (unsigned char*)R;                // 32 MB
    unsigned char* X8   = (unsigned char*)(R + 33554432);   // 32 MB
    u16*           hidA = (u16*)(R + 67108864);             // 25.6 MB (then xvp)
    u16*           xvp  = (u16*)(R + 67108864);             // 38.4 MB

    detect_k<<<1, 256, 0, stream>>>(h, mflag);
    prep_misc_k<<<418, 256, 0, stream>>>(W00, W11, bW1, Wv, Wcoord, aW2, bW2,
                                         W00T, W1p, W2p, w1tp, w_eff,
                                         W2ah, W11T, mflag);
    prep_w1s_k<<<256, 256, 0, stream>>>(aW1, Ws_w, Ws_b, ab1, W1sh, b1p, mflag);

    // ---- atom head (uses hidA region; must finish before packx8 overwrites) ----
    mlp1_k<<<784, 256, 0, stream>>>(h, W1sh, b1p, hidA, mflag);
    mlp_l2_k<<<782, 256, 0, stream>>>(hidA, W2ah, ab2, d_out, mflag);

    // ---- one pass over h: X8 (planar) + xvp + fused r0 ----
    packx8_k<<<12500, 256, 0, stream>>>(h, xvp, w_eff, X8, d_out, mflag);

    // ---- PQ8 (planar Q) ----
    gemm8n_k<<<1960, 256, 0, stream>>>(h, xvp, W00T, W11T, PQ8,
                                       16.f * INV_SQRT_FAN,
                                       16.f * INV_SQRT_FAN * INV_SQRT3, mflag);
    tp_k<<<50000, 256, 0, stream>>>(ei, PQ8, X8, tp);

    // ---- bond head ----
    bond_fused_k<<<3125, 256, 0, stream>>>(e_fin, W1p, bb1, W2p, bb2,
                                           tp, w1tp, d_out, 950000L, mflag);
}

// Round 3
// 483.417 us; speedup vs baseline: 1.1648x; 1.0367x over previous
//
#include <hip/hip_runtime.h>

typedef unsigned short u16;
typedef unsigned int u32;
typedef float f32x4 __attribute__((ext_vector_type(4)));
typedef float f32x2 __attribute__((ext_vector_type(2)));
typedef short s16x8 __attribute__((ext_vector_type(8)));
typedef __bf16 bf16x8 __attribute__((ext_vector_type(8)));

#define NNODE 50000
#define NEDGE 200000
#define INV_SQRT3 0.57735026918962576f
#define INV_SQRT_FAN 0.0034938562148434216f  /* 1/sqrt(256^2+128^2) */

__device__ inline float b2f(u16 x) {
    unsigned u = ((unsigned)x) << 16;
    return __builtin_bit_cast(float, u);
}
__device__ inline u16 f2b(float f) {
    unsigned u = __builtin_bit_cast(unsigned, f);
    unsigned r = u + 0x7FFFu + ((u >> 16) & 1u);
    return (u16)(r >> 16);
}
__device__ inline float silu(float v) { return v / (1.f + __expf(-v)); }

__device__ inline float ld1(const void* p, long i, int m) {
    return m ? ((const float*)p)[i] : b2f(((const u16*)p)[i]);
}
__device__ inline void stout(void* o, long i, float v, int m) {
    if (m) ((float*)o)[i] = v; else ((u16*)o)[i] = f2b(v);
}

// ---------------- fp8 e4m3fn codec ----------------
#if defined(__has_builtin)
# if __has_builtin(__builtin_amdgcn_cvt_pk_f32_fp8) && __has_builtin(__builtin_amdgcn_cvt_pk_fp8_f32)
#  define HAVE_FP8 1
# endif
#endif
#ifndef HAVE_FP8
# define HAVE_FP8 0
#endif

__device__ inline int f2e4m3_soft(float f) {
    unsigned u = __builtin_bit_cast(unsigned, f);
    int s = (u >> 24) & 0x80;
    float a = __builtin_fabsf(f);
    if (a >= 464.f) return s | 0x7E;
    if (a < 0.015625f) {
        int q = (int)(a * 512.f + 0.5f);
        return s | q;
    }
    int e = (int)((u >> 23) & 0xFF) - 127;
    unsigned m = u & 0x7FFFFF;
    unsigned mq = (m + 0x80000) >> 20;
    if (mq == 8) { mq = 0; e += 1; }
    if (e > 8) return s | 0x7E;
    return s | ((e + 7) << 3) | (int)mq;
}
__device__ inline float e4m3f_soft(int b) {
    int em = b & 0x7F;
    float v;
    if (em >> 3) {
        unsigned bits = ((unsigned)((em >> 3) + 120) << 23) | ((unsigned)(em & 7) << 20);
        v = __builtin_bit_cast(float, bits);
    } else {
        v = (float)em * 0.001953125f;
    }
    return (b & 0x80) ? -v : v;
}
__device__ inline int enc2(float a, float b) {
#if HAVE_FP8
    return __builtin_amdgcn_cvt_pk_fp8_f32(a, b, 0, false) & 0xFFFF;
#else
    return f2e4m3_soft(a) | (f2e4m3_soft(b) << 8);
#endif
}
__device__ inline unsigned char enc1(float a) { return (unsigned char)(enc2(a, a) & 0xFF); }

__device__ inline float dot8(unsigned p, unsigned x, float acc) {
#if HAVE_FP8
    f32x2 p0 = __builtin_amdgcn_cvt_pk_f32_fp8((int)p, false);
    f32x2 p1 = __builtin_amdgcn_cvt_pk_f32_fp8((int)p, true);
    f32x2 x0 = __builtin_amdgcn_cvt_pk_f32_fp8((int)x, false);
    f32x2 x1 = __builtin_amdgcn_cvt_pk_f32_fp8((int)x, true);
    return acc + p0.x * x0.x + p0.y * x0.y + p1.x * x1.x + p1.y * x1.y;
#else
    float r = acc;
#pragma unroll
    for (int i = 0; i < 4; ++i)
        r += e4m3f_soft((p >> (8 * i)) & 0xFF) * e4m3f_soft((x >> (8 * i)) & 0xFF);
    return r;
#endif
}

// MFMA wrapper tolerant to either builtin signature.
template <typename V>
__device__ auto mfma_sel(V a, V b, f32x4 c, int)
    -> decltype(__builtin_amdgcn_mfma_f32_16x16x32_bf16(a, b, c, 0, 0, 0)) {
    return __builtin_amdgcn_mfma_f32_16x16x32_bf16(a, b, c, 0, 0, 0);
}
template <typename V>
__device__ f32x4 mfma_sel(V a, V b, f32x4 c, long) {
    bf16x8 aa = __builtin_bit_cast(bf16x8, a);
    bf16x8 bb = __builtin_bit_cast(bf16x8, b);
    return __builtin_amdgcn_mfma_f32_16x16x32_bf16(aa, bb, c, 0, 0, 0);
}
__device__ inline f32x4 mfma_bf16(s16x8 a, s16x8 b, f32x4 c) {
    return mfma_sel(a, b, c, 0);
}

// ---------------- async global -> LDS (16 B per lane, wave-uniform LDS base) ----
typedef __attribute__((address_space(1))) u32 AS1u32;
typedef __attribute__((address_space(3))) u32 AS3u32;
__device__ __forceinline__ void async16(const void* g, void* l) {
    __builtin_amdgcn_global_load_lds((AS1u32*)g, (AS3u32*)l, 16, 0, 0);
}

// ---------------- detect input storage dtype ----------------
__global__ __launch_bounds__(256) void detect_k(const void* __restrict__ h, int* __restrict__ flag) {
    int t = threadIdx.x;
    u16 w = ((const u16*)h)[2 * t];
    int tb = (w >> 8) & 0x7F;
    bool pl = (tb >= 0x38 && tb <= 0x41);
    unsigned long long b = __ballot(pl);
    __shared__ int cnt[4];
    if ((t & 63) == 0) cnt[t >> 6] = __popcll(b);
    __syncthreads();
    if (t == 0) {
        int s = cnt[0] + cnt[1] + cnt[2] + cnt[3];
        flag[0] = (s < 128) ? 1 : 0;  // 1 = f32 storage
    }
}

// ---------------- prep: transposes / packs / w_eff ----------------
__global__ __launch_bounds__(256) void prep_misc_k(
    const void* __restrict__ W00, const void* __restrict__ W11,
    const void* __restrict__ bW1, const void* __restrict__ Wv,
    const void* __restrict__ Wcoord, const void* __restrict__ aW2,
    const void* __restrict__ bW2,
    u16* __restrict__ W00T, u16* __restrict__ W1p, u16* __restrict__ W2p,
    float* __restrict__ w1tp, float* __restrict__ w_eff,
    u16* __restrict__ W2ah, u16* __restrict__ W11T,
    const int* __restrict__ mflag)
{
    const int m = *mflag;
    int u = blockIdx.x * 256 + threadIdx.x;
    if (u < 65536) {                 // W00T[j][i] = W00[i][j]
        int j = u >> 8, i = u & 255;
        W00T[u] = f2b(ld1(W00, (long)i * 256 + j, m));
    } else if (u < 81920) {          // W1p: bond W1 fragment pack
        int v = u - 65536;
        int j = v & 7, ln = (v >> 3) & 63, tk = v >> 9;  // tk 0..31
        int tn = tk >> 1, kt = tk & 1;
        int hrow = tn * 16 + (ln & 15);
        int k = kt * 32 + (ln >> 4) * 8 + j;
        W1p[v] = f2b(ld1(bW1, (long)hrow * 65 + 1 + k, m));
    } else if (u < 86016) {          // W2p: bond W2 fragment pack (padded o>=5 -> 0)
        int v = u - 81920;
        int j = v & 7, ln = (v >> 3) & 63, kt = v >> 9;  // kt 0..7
        int o = ln & 15;
        int k = kt * 32 + (ln >> 4) * 8 + j;
        W2p[v] = (o < 5) ? f2b(ld1(bW2, (long)o * 256 + k, m)) : (u16)0;
    } else if (u < 86272) {          // w1tp
        int hd = u - 86016;
        w1tp[hd] = ld1(bW1, (long)hd * 65, m);
    } else if (u < 86400) {          // w_eff
        int c = u - 86272;
        float acc = 0.f;
        for (int d = 0; d < 128; ++d)
            acc += ld1(Wcoord, d, m) * ld1(Wv, (long)d * 128 + c, m);
        w_eff[c] = acc;
    } else if (u < 90496) {          // atom W2 (16x256)
        int v = u - 86400;
        W2ah[v] = f2b(ld1(aW2, v, m));
    } else if (u < 106880) {         // W11T[d][c] = W11[c][d]
        int v = u - 90496;
        int d = v >> 7, c = v & 127;
        W11T[v] = f2b(ld1(W11, (long)c * 128 + d, m));
    }
}

// W1s = atom_W1 @ Ws_w; b1p = atom_W1@Ws_b + atom_b1
__global__ __launch_bounds__(256) void prep_w1s_k(
    const void* __restrict__ aW1, const void* __restrict__ Wsw,
    const void* __restrict__ Wsb, const void* __restrict__ ab1,
    u16* __restrict__ W1sh, float* __restrict__ b1p,
    const int* __restrict__ mflag)
{
    const int m = *mflag;
    int hd = blockIdx.x, s = threadIdx.x;
    float acc = 0.f;
    for (int j = 0; j < 256; ++j)
        acc += ld1(aW1, (long)hd * 256 + j, m) * ld1(Wsw, (long)j * 256 + s, m);
    W1sh[hd * 256 + s] = f2b(acc);
    if (s == 0) {
        float b = ld1(ab1, hd, m);
        for (int j = 0; j < 256; ++j)
            b += ld1(aW1, (long)hd * 256 + j, m) * ld1(Wsb, j, m);
        b1p[hd] = b;
    }
}

// ---------------- zero the atom-head f32 partial buffer ----------------
__global__ __launch_bounds__(256) void zero_k(float4* __restrict__ p) {
    int t = blockIdx.x * 256 + threadIdx.x;
    if (t < 200000) p[t] = float4{0.f, 0.f, 0.f, 0.f};
}

// ---------------- shared pipelined 128x128 GEMM core (bf16 A via async16) -------
// C[128 x 128] += A[128 x K] * B^T, A u16 node-major, B row-major [outcol][K].
// LDS: S[0..16383] u16 = A dbuf (2 x 4 KB) | B dbuf (2 x 4 KB), linear [row][32].
// Schedule: stage(t+1) issued BEFORE compute(t); one __syncthreads per K-step.
__device__ __forceinline__ void gemm_core_128(
    const u16* __restrict__ Aptr, int lda,
    const u16* __restrict__ Bt, int ldb, int bcol0,
    long bm0, int K, u16* __restrict__ S, f32x4 acc[4][4])
{
    u16* As = S;            // [2][4096] u16
    u16* Bs = S + 8192;     // [2][4096] u16
    int tid = threadIdx.x;
    int lane = tid & 63, wave = tid >> 6;
    int sr = lane >> 2, sc = (lane & 3) * 8;   // lane -> (row-in-16, k-offset)

    auto stage = [&](int buf, int k0) {
#pragma unroll
        for (int i = 0; i < 2; ++i) {
            int row = wave * 32 + i * 16 + sr;
            async16(Bt + (long)(bcol0 + row) * ldb + k0 + sc,
                    Bs + buf * 4096 + wave * 1024 + i * 512);
            long grow = bm0 + row; if (grow >= NNODE) grow = NNODE - 1;
            async16(Aptr + grow * (long)lda + k0 + sc,
                    As + buf * 4096 + wave * 1024 + i * 512);
        }
    };

    int NT = K >> 5;
    stage(0, 0);
    __syncthreads();
    int wm = (wave & 1) * 64, wn = (wave >> 1) * 64;
    int lm = lane & 15, quad = lane >> 4;
    for (int t = 0; t < NT; ++t) {
        int cur = t & 1;
        if (t + 1 < NT) stage(cur ^ 1, (t + 1) * 32);
        const u16* Ac = As + cur * 4096;
        const u16* Bc = Bs + cur * 4096;
        s16x8 af[4], bfr[4];
#pragma unroll
        for (int q = 0; q < 4; ++q) {
            af[q]  = *(const s16x8*)(Ac + (wm + q * 16 + lm) * 32 + quad * 8);
            bfr[q] = *(const s16x8*)(Bc + (wn + q * 16 + lm) * 32 + quad * 8);
        }
#pragma unroll
        for (int i = 0; i < 4; ++i)
#pragma unroll
            for (int j = 0; j < 4; ++j)
                acc[i][j] = mfma_bf16(af[i], bfr[j], acc[i][j]);
        __syncthreads();
    }
}

// ---------------- atom MLP: fused l1+l2 (split-K over col-halves, f32 atomics) --
__global__ __launch_bounds__(256) void mlp1_k(
    const u16* __restrict__ Xs16, const u16* __restrict__ Bh,
    const float* __restrict__ b1p, const u16* __restrict__ W2ah,
    float* __restrict__ outP)
{
    __shared__ __align__(16) u16 S[17408];   // staging (16384) then hid tile [128][136]
    int bid = blockIdx.x;
    int x = bid & 7, s = bid >> 3;
    int rb = (s >> 1) * 8 + x, cb = s & 1;   // needs grid = 8*98 = 784 blocks
    if (rb >= 391) return;
    long bm0 = (long)rb * 128;
    int bn0 = cb * 128;
    f32x4 acc[4][4] = {};
    gemm_core_128(Xs16, 256, Bh, 256, bn0, bm0, 256, S, acc);

    int tid = threadIdx.x, lane = tid & 63, wave = tid >> 6;
    int wm = (wave & 1) * 64, wn = (wave >> 1) * 64;
    int lm = lane & 15, quad = lane >> 4;
    // silu+bias -> bf16 hid tile in LDS, stride 136
#pragma unroll
    for (int j = 0; j < 4; ++j) {
        int col = wn + j * 16 + lm;
        float bb = b1p[bn0 + col];
#pragma unroll
        for (int i = 0; i < 4; ++i)
#pragma unroll
            for (int rr = 0; rr < 4; ++rr)
                S[(wm + i * 16 + quad * 4 + rr) * 136 + col] = f2b(silu(acc[i][j][rr] + bb));
    }
    __syncthreads();
    // layer 2 partial: out[128 x 16] over this block's 128 hidden cols
    const u16* wp = W2ah + lm * 256 + bn0;
#pragma unroll
    for (int rg = 0; rg < 2; ++rg) {
        int r0 = wave * 32 + rg * 16;
        f32x4 a2 = {0.f, 0.f, 0.f, 0.f};
#pragma unroll
        for (int k0 = 0; k0 < 128; k0 += 32) {
            s16x8 a = *(const s16x8*)(S + (r0 + lm) * 136 + k0 + quad * 8);
            s16x8 b = *(const s16x8*)(wp + k0 + quad * 8);
            a2 = mfma_bf16(a, b, a2);
        }
#pragma unroll
        for (int rr = 0; rr < 4; ++rr) {
            long grow = bm0 + r0 + quad * 4 + rr;
            if (grow < NNODE)
                atomicAdd(outP + grow * 16 + lm, a2[rr]);
        }
    }
}

// ---------------- atom head finalize: bias + dtype store ----------------
__global__ __launch_bounds__(256) void fin_atom_k(
    const float* __restrict__ outP, const void* __restrict__ b2v,
    void* __restrict__ out, const int* __restrict__ mflag)
{
    const int m = *mflag;
    int t = blockIdx.x * 256 + threadIdx.x;   // 800000 exactly
    stout(out, t, outP[t] + ld1(b2v, t & 15, m), m);
}

// ---------------- merged pack: Xs16, X8 (planar vec), xvp, r0 — one pass over h -
__global__ __launch_bounds__(256) void packx8_k(
    const void* __restrict__ h, u16* __restrict__ xvp,
    const float* __restrict__ w_eff, unsigned char* __restrict__ X8,
    u16* __restrict__ Xs16, void* __restrict__ out,
    const int* __restrict__ mflag)
{
    const int m = *mflag;
    int lane = threadIdx.x & 63, w = threadIdx.x >> 6;
    int node = blockIdx.x * 4 + w;
    if (node >= NNODE) return;
    // scalar part: 4 elems/lane -> fp8 + bf16
    float s4[4];
    if (m) {
        float4 v = *(const float4*)((const float*)h + (long)node * 640 + lane * 4);
        s4[0] = v.x; s4[1] = v.y; s4[2] = v.z; s4[3] = v.w;
    } else {
        ushort4 v = *(const ushort4*)((const u16*)h + (long)node * 640 + lane * 4);
        s4[0] = b2f(v.x); s4[1] = b2f(v.y); s4[2] = b2f(v.z); s4[3] = b2f(v.w);
    }
    unsigned sp = (unsigned)enc2(s4[0], s4[1]) | ((unsigned)enc2(s4[2], s4[3]) << 16);
    *(unsigned*)(X8 + (long)node * 640 + lane * 4) = sp;
    u16 sx[4] = {f2b(s4[0]), f2b(s4[1]), f2b(s4[2]), f2b(s4[3])};
    *(ushort4*)(Xs16 + (long)node * 256 + lane * 4) = *(const ushort4*)sx;
    // vector part: 6 elems/lane (c=2*lane, 2*lane+1; z=0,1,2 interleaved)
    float a[6];
    if (m) {
        const float* p = (const float*)h + (long)node * 640 + 256 + lane * 6;
        float2 v0 = *(const float2*)p;
        float2 v1 = *(const float2*)(p + 2);
        float2 v2 = *(const float2*)(p + 4);
        a[0] = v0.x; a[1] = v0.y; a[2] = v1.x; a[3] = v1.y; a[4] = v2.x; a[5] = v2.y;
    } else {
        const u16* p = (const u16*)h + (long)node * 640 + 256 + lane * 6;
        ushort2 v0 = *(const ushort2*)p;
        ushort2 v1 = *(const ushort2*)(p + 2);
        ushort2 v2 = *(const ushort2*)(p + 4);
        a[0] = b2f(v0.x); a[1] = b2f(v0.y); a[2] = b2f(v1.x);
        a[3] = b2f(v1.y); a[4] = b2f(v2.x); a[5] = b2f(v2.y);
    }
#pragma unroll
    for (int z = 0; z < 3; ++z) {
        unsigned pk = (unsigned)f2b(a[z]) | ((unsigned)f2b(a[z + 3]) << 16);
        *(unsigned*)(xvp + (long)z * 6400000 + (long)node * 128 + lane * 2) = pk;
        *(unsigned short*)(X8 + (long)node * 640 + 256 + z * 128 + lane * 2) =
            (unsigned short)enc2(a[z], a[z + 3]);
    }
    // fused r0
    float2 we = *(const float2*)(w_eff + lane * 2);
    float s0 = a[0] * we.x + a[3] * we.y;
    float s1 = a[1] * we.x + a[4] * we.y;
    float s2 = a[2] * we.x + a[5] * we.y;
#pragma unroll
    for (int off = 32; off > 0; off >>= 1) {
        s0 += __shfl_down(s0, off);
        s1 += __shfl_down(s1, off);
        s2 += __shfl_down(s2, off);
    }
    if (lane == 0) {
        stout(out, 800000L + (long)node * 3 + 0, s0, m);
        stout(out, 800000L + (long)node * 3 + 1, s1, m);
        stout(out, 800000L + (long)node * 3 + 2, s2, m);
    }
}

// ---------------- combined PQ GEMM -> fp8 (planar Q), pipelined core ------------
// cb 0,1: P = Xs16@W00 (K=256) -> cols cb*128. cb 2,3,4: Q_z = xvp_z@W11 (K=128)
// -> planar cols 256 + z*128 (matches packx8_k's X8 layout).
__global__ __launch_bounds__(256) void gemm8n_k(
    const u16* __restrict__ Xs16, const u16* __restrict__ xvp,
    const u16* __restrict__ W00T, const u16* __restrict__ W11T,
    unsigned char* __restrict__ PQ8, float s00, float s11)
{
    __shared__ __align__(16) u16 S[16384];
    int bid = blockIdx.x;
    int x = bid & 7, s = bid >> 3;
    int rb = (s / 5) * 8 + x, cb = s % 5;    // grid = 8*245 = 1960 blocks
    if (rb >= 391) return;
    const bool qp = (cb >= 2);
    int z = cb - 2;
    long bm0 = (long)rb * 128;
    f32x4 acc[4][4] = {};
    if (qp)
        gemm_core_128(xvp + (long)z * 6400000, 128, W11T, 128, 0, bm0, 128, S, acc);
    else
        gemm_core_128(Xs16, 256, W00T, 256, cb * 128, bm0, 256, S, acc);

    float scale = qp ? s11 : s00;
    int colbase = qp ? (256 + z * 128) : cb * 128;
    unsigned char* C8 = (unsigned char*)S;
    int tid = threadIdx.x, lane = tid & 63, wave = tid >> 6;
    int wm = (wave & 1) * 64, wn = (wave >> 1) * 64;
    int lm = lane & 15, quad = lane >> 4;
#pragma unroll
    for (int j = 0; j < 4; ++j) {
        int col = wn + j * 16 + lm;
#pragma unroll
        for (int i = 0; i < 4; ++i)
#pragma unroll
            for (int rr = 0; rr < 4; ++rr) {
                int row = wm + i * 16 + quad * 4 + rr;
                C8[row * 128 + col] = enc1(scale * acc[i][j][rr]);
            }
    }
    __syncthreads();
#pragma unroll
    for (int v = 0; v < 4; ++v) {
        int idx = v * 256 + tid;
        int row = idx >> 3, seg = idx & 7;
        long grow = bm0 + row;
        if (grow < NNODE)
            *(uint4*)(PQ8 + grow * 640 + colbase + seg * 16) =
                *(const uint4*)(C8 + row * 128 + seg * 16);
    }
}

// ---------------- bond head: MFMA both layers, per-wave LDS transpose -----------
__global__ __launch_bounds__(256) void bond_fused_k(
    const void* __restrict__ A, const u16* __restrict__ W1p,
    const void* __restrict__ b1v, const u16* __restrict__ W2p,
    const void* __restrict__ b2v, const float* __restrict__ tp,
    const float* __restrict__ w1tp, void* __restrict__ out, long obase,
    const int* __restrict__ mflag)
{
    const int m = *mflag;
    __shared__ __align__(16) u16 hidS[4][16][264];
    int tid = threadIdx.x, lane = tid & 63, w = tid >> 6;
    int lm = lane & 15, quad = lane >> 4;
    int e0 = (blockIdx.x * 4 + w) * 16;
    s16x8 af0, af1;
    long base = (long)(e0 + lm) * 64 + quad * 8;
    if (m) {
        const float* ap = (const float*)A + base;
        float4 a0 = *(const float4*)ap,        a1 = *(const float4*)(ap + 4);
        float4 a2 = *(const float4*)(ap + 32), a3 = *(const float4*)(ap + 36);
        u16 t0[8] = {f2b(a0.x), f2b(a0.y), f2b(a0.z), f2b(a0.w),
                     f2b(a1.x), f2b(a1.y), f2b(a1.z), f2b(a1.w)};
        u16 t1[8] = {f2b(a2.x), f2b(a2.y), f2b(a2.z), f2b(a2.w),
                     f2b(a3.x), f2b(a3.y), f2b(a3.z), f2b(a3.w)};
        af0 = *(const s16x8*)t0; af1 = *(const s16x8*)t1;
    } else {
        af0 = *(const s16x8*)((const u16*)A + base);
        af1 = *(const s16x8*)((const u16*)A + base + 32);
    }
    float4 tpv = *(const float4*)(tp + e0 + quad * 4);
    float tpr[4] = {tpv.x, tpv.y, tpv.z, tpv.w};
    f32x4 acc1[16];
#pragma unroll
    for (int tn = 0; tn < 16; ++tn) {
        s16x8 b0 = *(const s16x8*)(W1p + ((tn * 2 + 0) * 64 + lane) * 8);
        s16x8 b1f = *(const s16x8*)(W1p + ((tn * 2 + 1) * 64 + lane) * 8);
        f32x4 a = {0.f, 0.f, 0.f, 0.f};
        a = mfma_bf16(af0, b0, a);
        a = mfma_bf16(af1, b1f, a);
        acc1[tn] = a;
    }
#pragma unroll
    for (int tn = 0; tn < 16; ++tn) {
        int hcol = tn * 16 + lm;
        float bb = ld1(b1v, hcol, m);
        float wt = w1tp[hcol];
#pragma unroll
        for (int rr = 0; rr < 4; ++rr)
            hidS[w][quad * 4 + rr][hcol] = f2b(silu(acc1[tn][rr] + bb + tpr[rr] * wt));
    }
    f32x4 acc2 = {0.f, 0.f, 0.f, 0.f};
#pragma unroll
    for (int kt = 0; kt < 8; ++kt) {
        s16x8 a = *(const s16x8*)&hidS[w][lm][kt * 32 + quad * 8];
        s16x8 b = *(const s16x8*)(W2p + (kt * 64 + lane) * 8);
        acc2 = mfma_bf16(a, b, acc2);
    }
    if (lm < 5) {
        float b2 = ld1(b2v, lm, m);
#pragma unroll
        for (int rr = 0; rr < 4; ++rr) {
            int e = e0 + quad * 4 + rr;
            stout(out, obase + (long)e * 5 + lm, acc2[rr] + b2, m);
        }
    }
}

// ---------------- tp: 16-lanes-per-edge fp8 640-dot ----------------
__global__ __launch_bounds__(256) void tp_k(
    const int* __restrict__ ei, const unsigned char* __restrict__ PQ8,
    const unsigned char* __restrict__ X8, float* __restrict__ tp)
{
    int tid = threadIdx.x;
    int sub = tid & 15;
    int e = blockIdx.x * 16 + (tid >> 4);
    if (e >= NEDGE) return;
    int row = ei[e], col = ei[NEDGE + e];
    const unsigned char* pq = PQ8 + (long)row * 640;
    const unsigned char* xp = X8 + (long)col * 640;
    uint4 p0 = *(const uint4*)(pq + sub * 16);
    uint4 x0 = *(const uint4*)(xp + sub * 16);
    uint4 p1 = *(const uint4*)(pq + 256 + sub * 16);
    uint4 x1 = *(const uint4*)(xp + 256 + sub * 16);
    uint2 p2 = *(const uint2*)(pq + 512 + sub * 8);
    uint2 x2 = *(const uint2*)(xp + 512 + sub * 8);
    float acc = 0.f;
    acc = dot8(p0.x, x0.x, acc); acc = dot8(p0.y, x0.y, acc);
    acc = dot8(p0.z, x0.z, acc); acc = dot8(p0.w, x0.w, acc);
    acc = dot8(p1.x, x1.x, acc); acc = dot8(p1.y, x1.y, acc);
    acc = dot8(p1.z, x1.z, acc); acc = dot8(p1.w, x1.w, acc);
    acc = dot8(p2.x, x2.x, acc); acc = dot8(p2.y, x2.y, acc);
#pragma unroll
    for (int off = 8; off > 0; off >>= 1) acc += __shfl_down(acc, off);
    if (sub == 0) tp[e] = acc * 0.0625f;
}

extern "C" void kernel_launch(void* const* d_in, const int* in_sizes, int n_in,
                              void* d_out, int out_size, void* d_ws, size_t ws_size,
                              hipStream_t stream) {
    (void)in_sizes; (void)n_in; (void)out_size; (void)ws_size;
    const void* h      = d_in[0];
    const void* e_fin  = d_in[1];
    const int*  ei     = (const int*)d_in[4];
    const void* Ws_w   = d_in[5];
    const void* Ws_b   = d_in[6];
    const void* Wv     = d_in[7];
    const void* Wcoord = d_in[8];
    const void* W00    = d_in[9];
    const void* W11    = d_in[10];
    const void* aW1    = d_in[11];
    const void* ab1    = d_in[12];
    const void* aW2    = d_in[13];
    const void* ab2    = d_in[14];
    const void* bW1    = d_in[15];
    const void* bb1    = d_in[16];
    const void* bW2    = d_in[17];
    const void* bb2    = d_in[18];

    char* ws = (char*)d_ws;
    int*   mflag = (int*)(ws + 0);
    float* w1tp  = (float*)(ws + 512);
    float* w_eff = (float*)(ws + 2048);
    float* b1p   = (float*)(ws + 3072);
    u16*   W00T  = (u16*)(ws + 4096);       // -> 135168
    u16*   W1p   = (u16*)(ws + 135168);     // -> 167936
    u16*   W2p   = (u16*)(ws + 167936);     // -> 176128
    u16*   W1sh  = (u16*)(ws + 176128);     // -> 307200
    u16*   W2ah  = (u16*)(ws + 307200);     // -> 315392
    u16*   W11T  = (u16*)(ws + 315392);     // -> 348160
    float* tp    = (float*)(ws + 348160);   // -> 1148160
    char*  R     = ws + 1149184;
    unsigned char* PQ8  = (unsigned char*)R;                  // 32 MB
    unsigned char* X8   = (unsigned char*)(R + 33554432);     // 32 MB
    u16*           xvp  = (u16*)(R + 67108864);               // 38.4 MB
    u16*           Xs16 = (u16*)(R + 105906176);              // 25.6 MB
    float*         outP = (float*)(R + 132120576);            // 3.2 MB

    detect_k<<<1, 256, 0, stream>>>(h, mflag);
    prep_misc_k<<<418, 256, 0, stream>>>(W00, W11, bW1, Wv, Wcoord, aW2, bW2,
                                         W00T, W1p, W2p, w1tp, w_eff,
                                         W2ah, W11T, mflag);
    prep_w1s_k<<<256, 256, 0, stream>>>(aW1, Ws_w, Ws_b, ab1, W1sh, b1p, mflag);
    zero_k<<<782, 256, 0, stream>>>((float4*)outP);

    // ---- one pass over h: Xs16 + X8 (planar) + xvp + fused r0 ----
    packx8_k<<<12500, 256, 0, stream>>>(h, xvp, w_eff, X8, Xs16, d_out, mflag);

    // ---- atom head: fused l1+l2 with f32 split-K atomics ----
    // grid MUST be 8*98 = 784: rb=(s>>1)*8+x covers rb 0..391 for both cb halves.
    mlp1_k<<<784, 256, 0, stream>>>(Xs16, W1sh, b1p, W2ah, outP);
    fin_atom_k<<<3125, 256, 0, stream>>>(outP, ab2, d_out, mflag);

    // ---- PQ8 (planar Q), all-bf16 async path ----
    gemm8n_k<<<1960, 256, 0, stream>>>(Xs16, xvp, W00T, W11T, PQ8,
                                       16.f * INV_SQRT_FAN,
                                       16.f * INV_SQRT_FAN * INV_SQRT3);
    tp_k<<<12500, 256, 0, stream>>>(ei, PQ8, X8, tp);

    // ---- bond head ----
    bond_fused_k<<<3125, 256, 0, stream>>>(e_fin, W1p, bb1, W2p, bb2,
                                           tp, w1tp, d_out, 950000L, mflag);
}